// Round 11
// baseline (326.797 us; speedup 1.0000x reference)
//
#include <hip/hip_runtime.h>

#define SEPS 1e-10f

typedef float v2f __attribute__((ext_vector_type(2)));

__device__ __forceinline__ float fast_rcp(float x) { return __builtin_amdgcn_rcpf(x); }
__device__ __forceinline__ float fast_exp(float x) { return __expf(x); }
__device__ __forceinline__ float fast_sigmoid(float x) {
    return fast_rcp(1.0f + fast_exp(-x));
}
__device__ __forceinline__ v2f splat2(float x) { v2f r; r.x = x; r.y = x; return r; }

// R=2 rows/thread on the proven round-7/8 structure:
// - L1+L2 k-loop ROLLED (caps live uniform weights -> no SGPR-spill VALU traffic)
// - j packed as v2f (v_pk_fma_f32 when the backend selects it)
// - BOTH rows share every weight load -> per-row scalar-cache traffic halves,
//   and per-iteration compute (2x16 pk-FMA) doubles against the same ~39
//   uniform loads -> SMEM latency/throughput stalls (the ~100us gap in r8)
//   should roughly halve.
// - waves_per_eu(4,8): VGPR budget 128; est. live ~95 -> ~5 waves/SIMD.
__global__ __launch_bounds__(256)
__attribute__((amdgpu_waves_per_eu(4, 8)))
void sinkhorn_mlp_kernel(
    const float* __restrict__ margins,
    const float* __restrict__ W1, const float* __restrict__ b1,
    const float* __restrict__ W2, const float* __restrict__ b2,
    const float* __restrict__ W3, const float* __restrict__ b3,
    const float* __restrict__ W4, const float* __restrict__ b4,
    float* __restrict__ out_mus, float* __restrict__ out_V, int n)
{
    const int tid = threadIdx.x;
    const size_t base = (size_t)blockIdx.x * 512;
    size_t r0 = base + tid;
    size_t r1 = base + 256 + tid;
    bool ok0 = r0 < (size_t)n, ok1 = r1 < (size_t)n;
    size_t rc0i = ok0 ? r0 : 0, rc1i = ok1 ? r1 : 0;

    // ---- load margins (6 floats/row, 8B-aligned) ----
    float m[2][6];
    {
        const float2* mp0 = reinterpret_cast<const float2*>(margins + rc0i * 6);
        float2 a = mp0[0], b = mp0[1], c = mp0[2];
        m[0][0] = a.x; m[0][1] = a.y; m[0][2] = b.x; m[0][3] = b.y; m[0][4] = c.x; m[0][5] = c.y;
        const float2* mp1 = reinterpret_cast<const float2*>(margins + rc1i * 6);
        float2 d = mp1[0], e = mp1[1], f = mp1[2];
        m[1][0] = d.x; m[1][1] = d.y; m[1][2] = e.x; m[1][3] = e.y; m[1][4] = f.x; m[1][5] = f.y;
    }

    // ---- layers 1+2 fused, j packed; both rows share weights ----
    v2f h2p[2][16];
    const v2f* b2v = reinterpret_cast<const v2f*>(b2);
#pragma unroll
    for (int jp = 0; jp < 16; ++jp) { v2f bb = b2v[jp]; h2p[0][jp] = bb; h2p[1][jp] = bb; }

#pragma unroll 1
    for (int k = 0; k < 64; ++k) {
        float bk = b1[k];
        float w0 = W1[k],       w1 = W1[64 + k],  w2 = W1[128 + k];
        float w3 = W1[192 + k], w4 = W1[256 + k], w5 = W1[320 + k];
        float t0 = bk, t1 = bk;
        t0 = fmaf(m[0][0], w0, t0);  t1 = fmaf(m[1][0], w0, t1);
        t0 = fmaf(m[0][1], w1, t0);  t1 = fmaf(m[1][1], w1, t1);
        t0 = fmaf(m[0][2], w2, t0);  t1 = fmaf(m[1][2], w2, t1);
        t0 = fmaf(m[0][3], w3, t0);  t1 = fmaf(m[1][3], w3, t1);
        t0 = fmaf(m[0][4], w4, t0);  t1 = fmaf(m[1][4], w4, t1);
        t0 = fmaf(m[0][5], w5, t0);  t1 = fmaf(m[1][5], w5, t1);
        t0 = fmaxf(t0, 0.0f);
        t1 = fmaxf(t1, 0.0f);
        v2f tv0 = splat2(t0), tv1 = splat2(t1);
        const v2f* w2r = reinterpret_cast<const v2f*>(W2 + k * 32);
#pragma unroll
        for (int jp = 0; jp < 16; ++jp) {
            v2f w = w2r[jp];
            h2p[0][jp] = __builtin_elementwise_fma(tv0, w, h2p[0][jp]);
            h2p[1][jp] = __builtin_elementwise_fma(tv1, w, h2p[1][jp]);
        }
    }

    // ---- layer 3 fused, packed, fully unrolled ----
    v2f h3p[2][8];
    const v2f* b3v = reinterpret_cast<const v2f*>(b3);
#pragma unroll
    for (int jp = 0; jp < 8; ++jp) { v2f bb = b3v[jp]; h3p[0][jp] = bb; h3p[1][jp] = bb; }
#pragma unroll
    for (int k = 0; k < 32; ++k) {
        float hk0 = (k & 1) ? h2p[0][k >> 1].y : h2p[0][k >> 1].x;
        float hk1 = (k & 1) ? h2p[1][k >> 1].y : h2p[1][k >> 1].x;
        v2f tv0 = splat2(fmaxf(hk0, 0.0f));
        v2f tv1 = splat2(fmaxf(hk1, 0.0f));
        const v2f* w3r = reinterpret_cast<const v2f*>(W3 + k * 16);
#pragma unroll
        for (int jp = 0; jp < 8; ++jp) {
            v2f w = w3r[jp];
            h3p[0][jp] = __builtin_elementwise_fma(tv0, w, h3p[0][jp]);
            h3p[1][jp] = __builtin_elementwise_fma(tv1, w, h3p[1][jp]);
        }
    }

    // ---- layer 4 fused, scalar (stride 9 breaks pairing), fully unrolled ----
    float pars[2][9];
#pragma unroll
    for (int j = 0; j < 9; ++j) { float bb = b4[j]; pars[0][j] = bb; pars[1][j] = bb; }
#pragma unroll
    for (int k = 0; k < 16; ++k) {
        float hk0 = (k & 1) ? h3p[0][k >> 1].y : h3p[0][k >> 1].x;
        float hk1 = (k & 1) ? h3p[1][k >> 1].y : h3p[1][k >> 1].x;
        float t0 = fmaxf(hk0, 0.0f);
        float t1 = fmaxf(hk1, 0.0f);
#pragma unroll
        for (int j = 0; j < 9; ++j) {
            float w = W4[k * 9 + j];
            pars[0][j] = fmaf(t0, w, pars[0][j]);
            pars[1][j] = fmaf(t1, w, pars[1][j]);
        }
    }

    // ---- heads + Sinkhorn + store, per row ----
#pragma unroll
    for (int rr = 0; rr < 2; ++rr) {
        float p0 = fast_exp(pars[rr][0]);
        float p1 = fast_exp(pars[rr][1]);
        float p2 = fast_exp(pars[rr][2]);
        float p3 = fast_exp(pars[rr][3]);

        float A00 = p3 * p0, A01 = p3 * p1, A02 = p3 * p2;
        float A10 = p3 * p1, A11 = p3 * p0, A12 = p3 * p1;
        float A20 = p3 * p2, A21 = p3 * p1, A22 = p3 * p0;

        float sm0 = fast_sigmoid(pars[rr][4]);
        float sm1 = fast_sigmoid(pars[rr][5]);
        float sf0 = fast_sigmoid(pars[rr][6]);
        float sf1 = fast_sigmoid(pars[rr][7]);
        float V   = fast_exp(pars[rr][8]);

        float M0 = m[rr][0], M1 = m[rr][1], M2 = m[rr][2];
        float F0 = m[rr][3], F1 = m[rr][4], F2 = m[rr][5];

        float rc0 = M0 * sm0, rc1 = M1 * sm1, rc2 = M2;
        float cc0 = F0 * sf0, cc1 = F1 * sf1, cc2 = F2;
        float mum0_0 = M0 * (1.0f - sm0);
        float mum0_1 = M1 * (1.0f - sm1);
        float mu0f_0 = F0 * (1.0f - sf0);
        float mu0f_1 = F1 * (1.0f - sf1);

#pragma unroll
        for (int it = 0; it < 10; ++it) {
            float f0 = rc0 * fast_rcp(A00 + A01 + A02 + SEPS);
            float f1 = rc1 * fast_rcp(A10 + A11 + A12 + SEPS);
            float f2 = rc2 * fast_rcp(A20 + A21 + A22 + SEPS);
            A00 *= f0; A01 *= f0; A02 *= f0;
            A10 *= f1; A11 *= f1; A12 *= f1;
            A20 *= f2; A21 *= f2; A22 *= f2;
            float g0 = cc0 * fast_rcp(A00 + A10 + A20 + SEPS);
            float g1 = cc1 * fast_rcp(A01 + A11 + A21 + SEPS);
            float g2 = cc2 * fast_rcp(A02 + A12 + A22 + SEPS);
            A00 *= g0; A10 *= g0; A20 *= g0;
            A01 *= g1; A11 *= g1; A21 *= g1;
            A02 *= g2; A12 *= g2; A22 *= g2;
        }

        bool okr = rr ? ok1 : ok0;
        size_t rw = rr ? r1 : r0;
        if (okr) {
            float4* o = reinterpret_cast<float4*>(out_mus + rw * 16);
            o[0] = make_float4(A00, A01, A02, mum0_0);
            o[1] = make_float4(A10, A11, A12, mum0_1);
            o[2] = make_float4(A20, A21, A22, 0.0f);
            o[3] = make_float4(mu0f_0, mu0f_1, 0.0f, 0.0f);
            out_V[rw] = V;
        }
    }
}

extern "C" void kernel_launch(void* const* d_in, const int* in_sizes, int n_in,
                              void* d_out, int out_size, void* d_ws, size_t ws_size,
                              hipStream_t stream) {
    const float* margins = (const float*)d_in[0];
    const float* W1 = (const float*)d_in[1];
    const float* b1 = (const float*)d_in[2];
    const float* W2 = (const float*)d_in[3];
    const float* b2 = (const float*)d_in[4];
    const float* W3 = (const float*)d_in[5];
    const float* b3 = (const float*)d_in[6];
    const float* W4 = (const float*)d_in[7];
    const float* b4 = (const float*)d_in[8];

    int n = in_sizes[0] / 6;
    float* out_mus = (float*)d_out;
    float* out_V   = out_mus + (size_t)n * 16;

    dim3 block(256);
    dim3 grid((n + 511) / 512);   // 2 rows per thread
    sinkhorn_mlp_kernel<<<grid, block, 0, stream>>>(
        margins, W1, b1, W2, b2, W3, b3, W4, b4, out_mus, out_V, n);
}

// Round 12
// 149.690 us; speedup vs baseline: 2.1832x; 2.1832x over previous
//
#include <hip/hip_runtime.h>

#define SEPS 1e-10f

typedef float v2f __attribute__((ext_vector_type(2)));

__device__ __forceinline__ float fast_rcp(float x) { return __builtin_amdgcn_rcpf(x); }
__device__ __forceinline__ float fast_exp(float x) { return __expf(x); }
__device__ __forceinline__ float fast_sigmoid(float x) {
    return fast_rcp(1.0f + fast_exp(-x));
}
__device__ __forceinline__ v2f splat2(float x) { v2f r; r.x = x; r.y = x; return r; }

// Round-8 structure (best: 192us rocprof) + ONE change: #pragma unroll 2 on
// the L1+L2 k-loop. Rationale: r8's gap over the ~73us VALU floor is the
// per-iteration uniform s_load burst (~39 scalar words) whose lgkmcnt wait is
// exposed every iteration under unroll 1. Unroll 2 batches two iterations'
// loads under one wait (~88cy compute per wait instead of ~44), while keeping
// live uniform scalars ~80 < 102 SGPRs (no r2/r4 spill pathology; rule-#20
// safe since unrolled bodies keep compile-time array indices).
__global__ __launch_bounds__(256)
__attribute__((amdgpu_waves_per_eu(4, 8)))
void sinkhorn_mlp_kernel(
    const float* __restrict__ margins,
    const float* __restrict__ W1, const float* __restrict__ b1,
    const float* __restrict__ W2, const float* __restrict__ b2,
    const float* __restrict__ W3, const float* __restrict__ b3,
    const float* __restrict__ W4, const float* __restrict__ b4,
    float* __restrict__ out_mus, float* __restrict__ out_V, int n)
{
    int r = blockIdx.x * blockDim.x + threadIdx.x;
    if (r >= n) return;

    // ---- load margins (6 floats, 8B-aligned) ----
    const float2* mp = reinterpret_cast<const float2*>(margins + (size_t)r * 6);
    float2 mv0 = mp[0], mv1 = mp[1], mv2 = mp[2];
    float m0 = mv0.x, m1 = mv0.y, m2 = mv1.x, m3 = mv1.y, m4 = mv2.x, m5 = mv2.y;

    // ---- layers 1+2 fused, j packed in pairs: h2p[jp] covers j=2jp,2jp+1 ----
    v2f h2p[16];
    const v2f* b2v = reinterpret_cast<const v2f*>(b2);
#pragma unroll
    for (int jp = 0; jp < 16; ++jp) h2p[jp] = b2v[jp];

#pragma unroll 2
    for (int k = 0; k < 64; ++k) {
        float t = b1[k];
        t = fmaf(m0, W1[k],       t);
        t = fmaf(m1, W1[64 + k],  t);
        t = fmaf(m2, W1[128 + k], t);
        t = fmaf(m3, W1[192 + k], t);
        t = fmaf(m4, W1[256 + k], t);
        t = fmaf(m5, W1[320 + k], t);
        t = fmaxf(t, 0.0f);
        v2f tv = splat2(t);
        const v2f* w2r = reinterpret_cast<const v2f*>(W2 + k * 32);
#pragma unroll
        for (int jp = 0; jp < 16; ++jp)
            h2p[jp] = __builtin_elementwise_fma(tv, w2r[jp], h2p[jp]);
    }

    // ---- layer 3 fused, packed (W3 rows: 16 floats, 8B-aligned) ----
    v2f h3p[8];
    const v2f* b3v = reinterpret_cast<const v2f*>(b3);
#pragma unroll
    for (int jp = 0; jp < 8; ++jp) h3p[jp] = b3v[jp];
#pragma unroll
    for (int k = 0; k < 32; ++k) {
        float hk = (k & 1) ? h2p[k >> 1].y : h2p[k >> 1].x;   // compile-time select
        float t = fmaxf(hk, 0.0f);
        v2f tv = splat2(t);
        const v2f* w3r = reinterpret_cast<const v2f*>(W3 + k * 16);
#pragma unroll
        for (int jp = 0; jp < 8; ++jp)
            h3p[jp] = __builtin_elementwise_fma(tv, w3r[jp], h3p[jp]);
    }

    // ---- layer 4 fused, scalar (row stride 9 floats -> unaligned pairs) ----
    float pars[9];
#pragma unroll
    for (int j = 0; j < 9; ++j) pars[j] = b4[j];
#pragma unroll
    for (int k = 0; k < 16; ++k) {
        float hk = (k & 1) ? h3p[k >> 1].y : h3p[k >> 1].x;
        float t = fmaxf(hk, 0.0f);
#pragma unroll
        for (int j = 0; j < 9; ++j) pars[j] = fmaf(t, W4[k * 9 + j], pars[j]);
    }

    // ---- heads ----
    float p0 = fast_exp(pars[0]);
    float p1 = fast_exp(pars[1]);
    float p2 = fast_exp(pars[2]);
    float p3 = fast_exp(pars[3]);

    float A00 = p3 * p0, A01 = p3 * p1, A02 = p3 * p2;
    float A10 = p3 * p1, A11 = p3 * p0, A12 = p3 * p1;
    float A20 = p3 * p2, A21 = p3 * p1, A22 = p3 * p0;

    float sm0 = fast_sigmoid(pars[4]);
    float sm1 = fast_sigmoid(pars[5]);
    float sf0 = fast_sigmoid(pars[6]);
    float sf1 = fast_sigmoid(pars[7]);
    float V   = fast_exp(pars[8]);

    float rc0 = m0 * sm0, rc1 = m1 * sm1, rc2 = m2;   // row targets
    float cc0 = m3 * sf0, cc1 = m4 * sf1, cc2 = m5;   // col targets
    float mum0_0 = m0 * (1.0f - sm0);
    float mum0_1 = m1 * (1.0f - sm1);
    float mu0f_0 = m3 * (1.0f - sf0);
    float mu0f_1 = m4 * (1.0f - sf1);

    // ---- Sinkhorn: 10 iterations (register-resident 3x3, scalar) ----
#pragma unroll
    for (int it = 0; it < 10; ++it) {
        float f0 = rc0 * fast_rcp(A00 + A01 + A02 + SEPS);
        float f1 = rc1 * fast_rcp(A10 + A11 + A12 + SEPS);
        float f2 = rc2 * fast_rcp(A20 + A21 + A22 + SEPS);
        A00 *= f0; A01 *= f0; A02 *= f0;
        A10 *= f1; A11 *= f1; A12 *= f1;
        A20 *= f2; A21 *= f2; A22 *= f2;
        float g0 = cc0 * fast_rcp(A00 + A10 + A20 + SEPS);
        float g1 = cc1 * fast_rcp(A01 + A11 + A21 + SEPS);
        float g2 = cc2 * fast_rcp(A02 + A12 + A22 + SEPS);
        A00 *= g0; A10 *= g0; A20 *= g0;
        A01 *= g1; A11 *= g1; A21 *= g1;
        A02 *= g2; A12 *= g2; A22 *= g2;
    }

    // ---- output: mus (4x4 row-major) then V ----
    float4* o = reinterpret_cast<float4*>(out_mus + (size_t)r * 16);
    o[0] = make_float4(A00, A01, A02, mum0_0);
    o[1] = make_float4(A10, A11, A12, mum0_1);
    o[2] = make_float4(A20, A21, A22, 0.0f);
    o[3] = make_float4(mu0f_0, mu0f_1, 0.0f, 0.0f);
    out_V[r] = V;
}

extern "C" void kernel_launch(void* const* d_in, const int* in_sizes, int n_in,
                              void* d_out, int out_size, void* d_ws, size_t ws_size,
                              hipStream_t stream) {
    const float* margins = (const float*)d_in[0];
    const float* W1 = (const float*)d_in[1];
    const float* b1 = (const float*)d_in[2];
    const float* W2 = (const float*)d_in[3];
    const float* b2 = (const float*)d_in[4];
    const float* W3 = (const float*)d_in[5];
    const float* b3 = (const float*)d_in[6];
    const float* W4 = (const float*)d_in[7];
    const float* b4 = (const float*)d_in[8];

    int n = in_sizes[0] / 6;
    float* out_mus = (float*)d_out;
    float* out_V   = out_mus + (size_t)n * 16;

    dim3 block(256);
    dim3 grid((n + 255) / 256);
    sinkhorn_mlp_kernel<<<grid, block, 0, stream>>>(
        margins, W1, b1, W2, b2, W3, b3, W4, b4, out_mus, out_V, n);
}